// Round 9
// baseline (60.735 us; speedup 1.0000x reference)
//
#include <hip/hip_runtime.h>
#include <hip/hip_bf16.h>
#include <stdint.h>

typedef unsigned short u16;
typedef unsigned int   u32;
typedef unsigned long long u64;

#define N_ROWS 4096
#define DIM    512
#define NT32   128         // N_ROWS / 32 tiles per side
#define NPAIR32 8256       // NT32*(NT32+1)/2  (= 8 * 1032)
#define MOD3   729         // 3^6
#define NLEV   6           // levels v = 0..5
#define NKS    16          // DIM / 32 k-steps
#define NSLOT  64          // accumulator replication (de-contended atomics)

typedef __attribute__((ext_vector_type(4))) float f32x4;

// ---- workspace layout (byte offsets) ----
// zpack: fragment-packed FP8 e4m3 (layout proven R8, absmax 0). Block (R, s)
// for 16-row group R and k-step s is 512 B at ((R<<4)+s)*512; lane L's 8 B
// hold row R*16 + (L&15), k = s*32 + (L>>4)*8 + j.
#define WS_ZPK 0
#define WS_SQ  (N_ROWS * DIM)               // zpack is N*D bytes
#define WS_R   (WS_SQ + N_ROWS * 4)
#define WS_ACC (WS_R + N_ROWS * 4)          // float gsum2[64][8]; u32 gcnt2[64][8]

// ---------------------------------------------------------------------------
// Prep (byte-identical to R8): f32 -> fp8 e4m3 pack, scatter into zpack,
// row sum-of-squares (fp32), idx % 729, row 0 zeroes accumulators.
// ---------------------------------------------------------------------------
__global__ __launch_bounds__(256)
void prep_kernel(const float* __restrict__ z, const int* __restrict__ idx,
                 u64* __restrict__ zpack, float* __restrict__ sq,
                 int* __restrict__ rres, u32* __restrict__ acczero)
{
    const int lane = threadIdx.x & 63;
    const int row  = blockIdx.x * 4 + (threadIdx.x >> 6);
    const float4* zr = reinterpret_cast<const float4*>(z + (size_t)row * DIM) + lane * 2;
    float4 v0 = zr[0], v1 = zr[1];
    float f[8] = {v0.x, v0.y, v0.z, v0.w, v1.x, v1.y, v1.z, v1.w};
    float ss = 0.f;
#pragma unroll
    for (int k = 0; k < 8; ++k) ss += f[k] * f[k];
    int lo = __builtin_amdgcn_cvt_pk_fp8_f32(f[0], f[1], 0, false);
    lo     = __builtin_amdgcn_cvt_pk_fp8_f32(f[2], f[3], lo, true);
    int hi = __builtin_amdgcn_cvt_pk_fp8_f32(f[4], f[5], 0, false);
    hi     = __builtin_amdgcn_cvt_pk_fp8_f32(f[6], f[7], hi, true);
    const u64 pk = (u64)(u32)lo | ((u64)(u32)hi << 32);
    zpack[((size_t)((row >> 4) * 16 + (lane >> 2)) << 6)
          + (lane & 3) * 16 + (row & 15)] = pk;
#pragma unroll
    for (int off = 32; off > 0; off >>= 1) ss += __shfl_down(ss, off, 64);
    if (lane == 0) {
        sq[row]   = ss;
        rres[row] = idx[row] % MOD3;   // idx >= 0
    }
    if (row == 0) {
#pragma unroll
        for (int i = 0; i < 16; ++i) acczero[lane + i * 64] = 0u;
    }
}

// ---------------------------------------------------------------------------
// Epilogue (same math as R6-R8, proven absmax 0; 2x2 fragment grid now).
// ---------------------------------------------------------------------------
template<bool DIAG>
__device__ __forceinline__ void epilogue_acc(
    const f32x4 (&acc)[2][2], const float* sqI, const float* sqJ,
    const int* rI, const int* rJ, int lane,
    float (&lsum)[NLEV], u64& pcnt)
{
    const int rbase = (lane >> 4) * 4;   // C/D: row = (lane>>4)*4 + q, col = lane&15
    const int cbase = lane & 15;
#pragma unroll
    for (int m = 0; m < 2; ++m) {
        const int il0 = m * 16 + rbase;
#pragma unroll
        for (int n = 0; n < 2; ++n) {
            const int jl  = n * 16 + cbase;
            const float sqj = sqJ[jl];
            const int   rj  = rJ[jl];
#pragma unroll
            for (int q = 0; q < 4; ++q) {
                const int il = il0 + q;
                float d2 = fmaxf(sqI[il] + sqj - 2.0f * acc[m][n][q], 0.f);
                const float dist = __builtin_amdgcn_sqrtf(d2);   // v_sqrt_f32
                int dm = rI[il] - rj;
                dm += (dm >> 31) & MOD3;            // mod 729 into [0,729)
                const u32 x = (u32)dm;
                // v3 valuation capped at 6: 3^t | x <=> x*inv(3^t) <= thr_t
                int v =
                    (x * 2863311531u <= 1431655765u) +   // 3
                    (x *  954437177u <=  477218588u) +   // 9
                    (x * 1749801491u <=  159072862u) +   // 27
                    (x * 2014922929u <=   53024287u) +   // 81
                    (x * 3534952507u <=   17674762u) +   // 243
                    (x * 4041629033u <=    5891587u);    // 729 (x==0 -> 6)
                if (DIAG) {
                    v = (jl > il) ? v : 6;    // same tile: local upper-tri only
                }
                float tv = 1.0f;
                tv = (v == 1) ? (1.f / 3.f)   : tv;
                tv = (v == 2) ? (1.f / 9.f)   : tv;
                tv = (v == 3) ? (1.f / 27.f)  : tv;
                tv = (v == 4) ? (1.f / 81.f)  : tv;
                tv = (v == 5) ? (1.f / 243.f) : tv;
                const float dd  = dist - tv;
                const float sqd = dd * dd;
#pragma unroll
                for (int vv = 0; vv < NLEV; ++vv)
                    lsum[vv] += (v == vv) ? sqd : 0.f;
                pcnt += 1ull << (8 * v);            // 8-bit field per class (<=16)
            }
        }
    }
}

// ---------------------------------------------------------------------------
// Main: ONE WAVE per block, one 32x32 tile pair (ti <= tj), fp8 operands.
// TLP round: 8256 blocks -> 32 waves/CU offered; __launch_bounds__(64, 4)
// caps VGPR at 128 (acc 16 + 8-deep frags 64 + addr ~10 + misc) -> 4
// waves/SIMD, 2x R7, with an 8-deep static pipeline (load->use ~7 steps).
// Fragment addresses: 4 base pointers + compile-time offset:s*512 folding.
// ---------------------------------------------------------------------------
__global__ __launch_bounds__(64, 4)
void pair_kernel(const u64* __restrict__ zpack, const float* __restrict__ sq,
                 const int* __restrict__ rres, float* __restrict__ gsum2,
                 u32* __restrict__ gcnt2)
{
    __shared__ float sqI[32], sqJ[32];
    __shared__ int   rI[32], rJ[32];

    const int lane = threadIdx.x;

    // bijective XCD swizzle (8256 = 8 * 1032)
    const int wg = (blockIdx.x & 7) * (NPAIR32 / 8) + (blockIdx.x >> 3);
    int t = wg, ti = 0, rem = NT32;
    while (t >= rem) { t -= rem; ++ti; --rem; }
    const int tj = ti + t;
    const int I0 = ti * 32, J0 = tj * 32;

    // stage sq/rres for the two 32-row panels (wave-synchronous; compiler
    // orders ds_read-after-ds_write within the wave)
    if (lane < 32) {
        sqI[lane] = sq[I0 + lane];
        rI[lane]  = rres[I0 + lane];
    } else {
        const int s = lane - 32;
        sqJ[s] = sq[J0 + s];
        rJ[s]  = rres[J0 + s];
    }

    // 32-row tile = 16-row groups {2t, 2t+1}; frag (R, s) at u64 index
    // R*1024 + s*64 + lane. Base pointers + imm offset s*512 B (s<8 folds).
    const u64* pA0 = zpack + ((size_t)(2 * ti)     << 10) + lane;
    const u64* pA1 = zpack + ((size_t)(2 * ti + 1) << 10) + lane;
    const u64* pB0 = zpack + ((size_t)(2 * tj)     << 10) + lane;
    const u64* pB1 = zpack + ((size_t)(2 * tj + 1) << 10) + lane;

    f32x4 acc[2][2];
#pragma unroll
    for (int m = 0; m < 2; ++m)
#pragma unroll
        for (int n = 0; n < 2; ++n) acc[m][n] = (f32x4){0.f, 0.f, 0.f, 0.f};

    long A[8][2], B[8][2];

#define LOADF(d, s)                                                            \
    {                                                                          \
        A[d][0] = (long)pA0[(s) * 64];                                         \
        A[d][1] = (long)pA1[(s) * 64];                                         \
        B[d][0] = (long)pB0[(s) * 64];                                         \
        B[d][1] = (long)pB1[(s) * 64];                                         \
    }
#define MFMA_ALL(d)                                                            \
    {                                                                          \
        _Pragma("unroll")                                                      \
        for (int m = 0; m < 2; ++m)                                            \
            _Pragma("unroll")                                                  \
            for (int n = 0; n < 2; ++n)                                        \
                acc[m][n] = __builtin_amdgcn_mfma_f32_16x16x32_fp8_fp8(        \
                    A[d][m], B[d][n], acc[m][n], 0, 0, 0);                     \
    }

    // 8-deep static pipeline; full unroll -> all indices compile-time.
#pragma unroll
    for (int s = 0; s < 7; ++s) LOADF(s, s);
#pragma unroll
    for (int s = 0; s < NKS; ++s) {
        if (s + 7 < NKS) LOADF((s + 7) & 7, s + 7);
        MFMA_ALL(s & 7);
    }
#undef LOADF
#undef MFMA_ALL

    // ---- fused epilogue (1 wave: no barriers anywhere) ----
    float lsum[NLEV] = {0.f, 0.f, 0.f, 0.f, 0.f, 0.f};
    u64 pcnt = 0ull;
    if (ti == tj) epilogue_acc<true >(acc, sqI, sqJ, rI, rJ, lane, lsum, pcnt);
    else          epilogue_acc<false>(acc, sqI, sqJ, rI, rJ, lane, lsum, pcnt);

    // wave shuffle reduce, then atomics into slot (blockIdx & 63)
    const int slot = (int)(blockIdx.x & (NSLOT - 1));
#pragma unroll
    for (int vv = 0; vv < NLEV; ++vv) {
        float s = lsum[vv];
        u32   c = (u32)((pcnt >> (8 * vv)) & 255ull);
#pragma unroll
        for (int off = 32; off > 0; off >>= 1) {
            s += __shfl_xor(s, off, 64);
            c += __shfl_xor(c, off, 64);
        }
        if (lane == 0) {
            atomicAdd(&gsum2[slot * 8 + vv], s);
            atomicAdd(&gcnt2[slot * 8 + vv], c);
        }
    }
}

// ---------------------------------------------------------------------------
// Finalize: one wave. Lane t owns slot t; shuffle-reduce the 64 slots.
// ---------------------------------------------------------------------------
__global__ __launch_bounds__(64)
void finalize_kernel(const float* __restrict__ gsum2,
                     const u32* __restrict__ gcnt2,
                     float* __restrict__ out)
{
    const int lane = threadIdx.x;
    float s[NLEV];
    u32   c[NLEV];
#pragma unroll
    for (int v = 0; v < NLEV; ++v) {
        s[v] = gsum2[lane * 8 + v];
        c[v] = gcnt2[lane * 8 + v];
    }
#pragma unroll
    for (int v = 0; v < NLEV; ++v) {
#pragma unroll
        for (int off = 32; off > 0; off >>= 1) {
            s[v] += __shfl_xor(s[v], off, 64);
            c[v] += __shfl_xor(c[v], off, 64);
        }
    }
    if (lane == 0) {
        const float w[NLEV] = {1.f, 1.f / 2.f, 1.f / 3.f, 1.f / 4.f, 1.f / 5.f, 1.f / 6.f};
        float total = 0.f, lc = 0.f;
#pragma unroll
        for (int v = 0; v < NLEV; ++v) {
            const float cnt = (float)c[v];
            const float mse = s[v] / fmaxf(cnt, 1.f);
            const bool  use = c[v] >= 2u;
            total += use ? w[v] * mse : 0.f;
            lc    += use ? 1.f : 0.f;
        }
        out[0] = total / fmaxf(lc, 1.f);
    }
}

// ---------------------------------------------------------------------------
extern "C" void kernel_launch(void* const* d_in, const int* in_sizes, int n_in,
                              void* d_out, int out_size, void* d_ws, size_t ws_size,
                              hipStream_t stream)
{
    const float* z   = (const float*)d_in[0];
    const int*   idx = (const int*)d_in[1];
    char* ws = (char*)d_ws;
    u64*   zpk  = (u64*)(ws + WS_ZPK);
    float* sq   = (float*)(ws + WS_SQ);
    int*   rres = (int*)(ws + WS_R);
    float* gsum2 = (float*)(ws + WS_ACC);
    u32*   gcnt2 = (u32*)(ws + WS_ACC + NSLOT * 8 * 4);
    float* out  = (float*)d_out;

    prep_kernel<<<N_ROWS / 4, 256, 0, stream>>>(z, idx, zpk, sq, rres, (u32*)gsum2);
    pair_kernel<<<NPAIR32, 64, 0, stream>>>(zpk, sq, rres, gsum2, gcnt2);
    finalize_kernel<<<1, 64, 0, stream>>>(gsum2, gcnt2, out);
}

// Round 10
// 37.391 us; speedup vs baseline: 1.6243x; 1.6243x over previous
//
#include <hip/hip_runtime.h>
#include <hip/hip_bf16.h>
#include <stdint.h>

typedef unsigned short u16;
typedef unsigned int   u32;
typedef unsigned long long u64;

#define N_ROWS 4096
#define DIM    512
#define NT64   64          // N_ROWS / 64 tiles per side
#define NPAIR64 2080       // NT64*(NT64+1)/2 (= 8 * 260)
#define MOD3   729         // 3^6
#define NLEV   6           // levels v = 0..5
#define NKP    8           // k-pairs; each covers 64 k (two 16x16x32 steps)
#define NSLOT  64          // accumulator replication (de-contended atomics)

typedef __attribute__((ext_vector_type(2))) long  long2v;
typedef __attribute__((ext_vector_type(4))) float f32x4;

// ---- workspace layout (byte offsets) ----
// zpack: fp8 e4m3, SUPERBLOCK layout. Superblock (R, s2) = 1 KB at
// ((R*8)+s2)*1024 covering 16-row group R, k-steps s=2*s2, 2*s2+1.
// u64 index within superblock: L*2 + h  (L = MFMA lane, h = step parity).
// One width-16 global_load_lds stages a whole superblock; ds_read_b128 at
// byte lane*16 yields (lane, h=0|1) = the two steps' fragments. Conflict-free
// (consecutive lanes -> consecutive 16B).
#define WS_ZPK 0
#define WS_SQ  (N_ROWS * DIM)               // zpack is N*D bytes (fp8)
#define WS_R   (WS_SQ + N_ROWS * 4)
#define WS_ACC (WS_R + N_ROWS * 4)          // float gsum2[64][8]; u32 gcnt2[64][8]

// ---------------------------------------------------------------------------
// Prep: f32 -> fp8 e4m3 pack, scatter into superblock zpack, row
// sum-of-squares (fp32 from original z), idx % 729, row 0 zeroes accums.
// Lane l owns k in [8l, 8l+8): s = l>>2, s2 = l>>3, h = (l>>2)&1,
// L = (l&3)*16 + (row&15).
// ---------------------------------------------------------------------------
__global__ __launch_bounds__(256)
void prep_kernel(const float* __restrict__ z, const int* __restrict__ idx,
                 u64* __restrict__ zpack, float* __restrict__ sq,
                 int* __restrict__ rres, u32* __restrict__ acczero)
{
    const int lane = threadIdx.x & 63;
    const int row  = blockIdx.x * 4 + (threadIdx.x >> 6);
    const float4* zr = reinterpret_cast<const float4*>(z + (size_t)row * DIM) + lane * 2;
    float4 v0 = zr[0], v1 = zr[1];
    float f[8] = {v0.x, v0.y, v0.z, v0.w, v1.x, v1.y, v1.z, v1.w};
    float ss = 0.f;
#pragma unroll
    for (int k = 0; k < 8; ++k) ss += f[k] * f[k];
    int lo = __builtin_amdgcn_cvt_pk_fp8_f32(f[0], f[1], 0, false);
    lo     = __builtin_amdgcn_cvt_pk_fp8_f32(f[2], f[3], lo, true);
    int hi = __builtin_amdgcn_cvt_pk_fp8_f32(f[4], f[5], 0, false);
    hi     = __builtin_amdgcn_cvt_pk_fp8_f32(f[6], f[7], hi, true);
    const u64 pk = (u64)(u32)lo | ((u64)(u32)hi << 32);
    zpack[((size_t)((row >> 4) * 8 + (lane >> 3)) << 7)
          + ((lane & 3) * 16 + (row & 15)) * 2 + ((lane >> 2) & 1)] = pk;
#pragma unroll
    for (int off = 32; off > 0; off >>= 1) ss += __shfl_down(ss, off, 64);
    if (lane == 0) {
        sq[row]   = ss;
        rres[row] = idx[row] % MOD3;   // idx >= 0
    }
    if (row == 0) {
#pragma unroll
        for (int i = 0; i < 16; ++i) acczero[lane + i * 64] = 0u;
    }
}

// ---------------------------------------------------------------------------
// Epilogue (verbatim math from R7, proven absmax 0; 4x4 fragment grid).
// ---------------------------------------------------------------------------
template<bool DIAG>
__device__ __forceinline__ void epilogue_acc(
    const f32x4 (&acc)[4][4], const float* sqI, const float* sqJ,
    const int* rI, const int* rJ, int lane,
    float (&lsum)[NLEV], u64& pcnt)
{
    const int rbase = (lane >> 4) * 4;   // C/D: row = (lane>>4)*4 + q, col = lane&15
    const int cbase = lane & 15;
#pragma unroll
    for (int m = 0; m < 4; ++m) {
        const int il0 = m * 16 + rbase;
#pragma unroll
        for (int n = 0; n < 4; ++n) {
            const int jl  = n * 16 + cbase;
            const float sqj = sqJ[jl];
            const int   rj  = rJ[jl];
#pragma unroll
            for (int q = 0; q < 4; ++q) {
                const int il = il0 + q;
                float d2 = fmaxf(sqI[il] + sqj - 2.0f * acc[m][n][q], 0.f);
                const float dist = __builtin_amdgcn_sqrtf(d2);   // v_sqrt_f32
                int dm = rI[il] - rj;
                dm += (dm >> 31) & MOD3;            // mod 729 into [0,729)
                const u32 x = (u32)dm;
                // v3 valuation capped at 6: 3^t | x <=> x*inv(3^t) <= thr_t
                int v =
                    (x * 2863311531u <= 1431655765u) +   // 3
                    (x *  954437177u <=  477218588u) +   // 9
                    (x * 1749801491u <=  159072862u) +   // 27
                    (x * 2014922929u <=   53024287u) +   // 81
                    (x * 3534952507u <=   17674762u) +   // 243
                    (x * 4041629033u <=    5891587u);    // 729 (x==0 -> 6)
                if (DIAG) {
                    v = (jl > il) ? v : 6;    // same tile: local upper-tri only
                }
                float tv = 1.0f;
                tv = (v == 1) ? (1.f / 3.f)   : tv;
                tv = (v == 2) ? (1.f / 9.f)   : tv;
                tv = (v == 3) ? (1.f / 27.f)  : tv;
                tv = (v == 4) ? (1.f / 81.f)  : tv;
                tv = (v == 5) ? (1.f / 243.f) : tv;
                const float dd  = dist - tv;
                const float sqd = dd * dd;
#pragma unroll
                for (int vv = 0; vv < NLEV; ++vv)
                    lsum[vv] += (v == vv) ? sqd : 0.f;
                pcnt += 1ull << (8 * v);            // 8-bit field per class (<=64)
            }
        }
    }
}

// ---------------------------------------------------------------------------
// Main: ONE WAVE per block, one 64x64 tile pair (ti <= tj), fp8 operands.
// Fire-and-forget pipeline (T4): global_load_lds (no dest VGPR -> compiler
// CANNOT sink it; R6/R8/R9's villain) into wave-private double-buffered LDS,
// counted inline-asm s_waitcnt vmcnt(8) (never 0 mid-loop) keeps 8 loads in
// flight across each iteration. 1-wave blocks: zero barriers. 17.4 KB LDS ->
// 9 blocks/CU; grid needs 8.125 -> all resident.
// ---------------------------------------------------------------------------
__global__ __launch_bounds__(64, 2)
void pair_kernel(const u64* __restrict__ zpack, const float* __restrict__ sq,
                 const int* __restrict__ rres, float* __restrict__ gsum2,
                 u32* __restrict__ gcnt2)
{
    __shared__ __align__(16) u64 sb[2][8][128];   // [buf][4 A-groups + 4 B-groups][1KB]
    __shared__ float sqI[64], sqJ[64];
    __shared__ int   rI[64], rJ[64];

    const int lane = threadIdx.x;

    // bijective XCD swizzle (2080 = 8 * 260)
    const int wg = (blockIdx.x & 7) * (NPAIR64 / 8) + (blockIdx.x >> 3);
    int t = wg, ti = 0, rem = NT64;
    while (t >= rem) { t -= rem; ++ti; --rem; }
    const int tj = ti + t;
    const int I0 = ti * 64, J0 = tj * 64;

    // stage sq/rres (4 oldest vmcnt entries; drained by the first vmcnt(8))
    __builtin_amdgcn_global_load_lds(
        (const __attribute__((address_space(1))) u32*)(sq + I0 + lane),
        (__attribute__((address_space(3))) u32*)sqI, 4, 0, 0);
    __builtin_amdgcn_global_load_lds(
        (const __attribute__((address_space(1))) u32*)(sq + J0 + lane),
        (__attribute__((address_space(3))) u32*)sqJ, 4, 0, 0);
    __builtin_amdgcn_global_load_lds(
        (const __attribute__((address_space(1))) u32*)(rres + I0 + lane),
        (__attribute__((address_space(3))) u32*)rI, 4, 0, 0);
    __builtin_amdgcn_global_load_lds(
        (const __attribute__((address_space(1))) u32*)(rres + J0 + lane),
        (__attribute__((address_space(3))) u32*)rJ, 4, 0, 0);

    const int RA = ti * 4, RB = tj * 4;   // 16-row group bases

    // stage one k-pair: 8 superblocks (4 A + 4 B), one width-16 glds each.
#define STAGE(buf, kp)                                                         \
    {                                                                          \
        _Pragma("unroll")                                                      \
        for (int g = 0; g < 4; ++g) {                                          \
            __builtin_amdgcn_global_load_lds(                                  \
                (const __attribute__((address_space(1))) u32*)                 \
                    (zpack + (((size_t)(RA + g) * 8 + (kp)) << 7) + lane * 2), \
                (__attribute__((address_space(3))) u32*)&sb[buf][g][0],        \
                16, 0, 0);                                                     \
            __builtin_amdgcn_global_load_lds(                                  \
                (const __attribute__((address_space(1))) u32*)                 \
                    (zpack + (((size_t)(RB + g) * 8 + (kp)) << 7) + lane * 2), \
                (__attribute__((address_space(3))) u32*)&sb[buf][4 + g][0],    \
                16, 0, 0);                                                     \
        }                                                                      \
    }

    f32x4 acc[4][4];
#pragma unroll
    for (int m = 0; m < 4; ++m)
#pragma unroll
        for (int n = 0; n < 4; ++n) acc[m][n] = (f32x4){0.f, 0.f, 0.f, 0.f};

    STAGE(0, 0);
#pragma unroll
    for (int kp = 0; kp < NKP; ++kp) {
        const int buf = kp & 1;
        if (kp + 1 < NKP) {
            STAGE(buf ^ 1, kp + 1);
            // oldest (sq/rres + this kp's 8) retired; next kp's 8 in flight
            asm volatile("s_waitcnt vmcnt(8)" ::: "memory");
        } else {
            asm volatile("s_waitcnt vmcnt(0)" ::: "memory");
        }
        __builtin_amdgcn_sched_barrier(0);
        long2v A[4], B[4];
#pragma unroll
        for (int g = 0; g < 4; ++g) {
            A[g] = reinterpret_cast<const long2v*>(&sb[buf][g][0])[lane];
            B[g] = reinterpret_cast<const long2v*>(&sb[buf][4 + g][0])[lane];
        }
#pragma unroll
        for (int h = 0; h < 2; ++h)
#pragma unroll
            for (int m = 0; m < 4; ++m)
#pragma unroll
                for (int n = 0; n < 4; ++n)
                    acc[m][n] = __builtin_amdgcn_mfma_f32_16x16x32_fp8_fp8(
                        A[m][h], B[n][h], acc[m][n], 0, 0, 0);
    }
#undef STAGE

    // ---- fused epilogue (1 wave: no barriers anywhere) ----
    float lsum[NLEV] = {0.f, 0.f, 0.f, 0.f, 0.f, 0.f};
    u64 pcnt = 0ull;
    if (ti == tj) epilogue_acc<true >(acc, sqI, sqJ, rI, rJ, lane, lsum, pcnt);
    else          epilogue_acc<false>(acc, sqI, sqJ, rI, rJ, lane, lsum, pcnt);

    // wave shuffle reduce, then atomics into slot (blockIdx & 63)
    const int slot = (int)(blockIdx.x & (NSLOT - 1));
#pragma unroll
    for (int vv = 0; vv < NLEV; ++vv) {
        float s = lsum[vv];
        u32   c = (u32)((pcnt >> (8 * vv)) & 255ull);
#pragma unroll
        for (int off = 32; off > 0; off >>= 1) {
            s += __shfl_xor(s, off, 64);
            c += __shfl_xor(c, off, 64);
        }
        if (lane == 0) {
            atomicAdd(&gsum2[slot * 8 + vv], s);
            atomicAdd(&gcnt2[slot * 8 + vv], c);
        }
    }
}

// ---------------------------------------------------------------------------
// Finalize: one wave. Lane t owns slot t; shuffle-reduce the 64 slots.
// ---------------------------------------------------------------------------
__global__ __launch_bounds__(64)
void finalize_kernel(const float* __restrict__ gsum2,
                     const u32* __restrict__ gcnt2,
                     float* __restrict__ out)
{
    const int lane = threadIdx.x;
    float s[NLEV];
    u32   c[NLEV];
#pragma unroll
    for (int v = 0; v < NLEV; ++v) {
        s[v] = gsum2[lane * 8 + v];
        c[v] = gcnt2[lane * 8 + v];
    }
#pragma unroll
    for (int v = 0; v < NLEV; ++v) {
#pragma unroll
        for (int off = 32; off > 0; off >>= 1) {
            s[v] += __shfl_xor(s[v], off, 64);
            c[v] += __shfl_xor(c[v], off, 64);
        }
    }
    if (lane == 0) {
        const float w[NLEV] = {1.f, 1.f / 2.f, 1.f / 3.f, 1.f / 4.f, 1.f / 5.f, 1.f / 6.f};
        float total = 0.f, lc = 0.f;
#pragma unroll
        for (int v = 0; v < NLEV; ++v) {
            const float cnt = (float)c[v];
            const float mse = s[v] / fmaxf(cnt, 1.f);
            const bool  use = c[v] >= 2u;
            total += use ? w[v] * mse : 0.f;
            lc    += use ? 1.f : 0.f;
        }
        out[0] = total / fmaxf(lc, 1.f);
    }
}

// ---------------------------------------------------------------------------
extern "C" void kernel_launch(void* const* d_in, const int* in_sizes, int n_in,
                              void* d_out, int out_size, void* d_ws, size_t ws_size,
                              hipStream_t stream)
{
    const float* z   = (const float*)d_in[0];
    const int*   idx = (const int*)d_in[1];
    char* ws = (char*)d_ws;
    u64*   zpk   = (u64*)(ws + WS_ZPK);
    float* sq    = (float*)(ws + WS_SQ);
    int*   rres  = (int*)(ws + WS_R);
    float* gsum2 = (float*)(ws + WS_ACC);
    u32*   gcnt2 = (u32*)(ws + WS_ACC + NSLOT * 8 * 4);
    float* out   = (float*)d_out;

    prep_kernel<<<N_ROWS / 4, 256, 0, stream>>>(z, idx, zpk, sq, rres, (u32*)gsum2);
    pair_kernel<<<NPAIR64, 64, 0, stream>>>(zpk, sq, rres, gsum2, gcnt2);
    finalize_kernel<<<1, 64, 0, stream>>>(gsum2, gcnt2, out);
}